// Round 9
// baseline (316.541 us; speedup 1.0000x reference)
//
#include <hip/hip_runtime.h>

// Problem constants (B=1)
#define T_LEN 2048
#define C_DIM 1024
#define H_NUM 16
#define D_DIM 64
#define QKV_N (3 * H_NUM * D_DIM)   // 3072
#define L_CHK 64
#define NC (T_LEN / L_CHK)          // 32

typedef _Float16 h8 __attribute__((ext_vector_type(8)));
typedef _Float16 h4 __attribute__((ext_vector_type(4)));
typedef float f32x4 __attribute__((ext_vector_type(4)));

// ---------------------------------------------------------------------------
// Fused fp32 -> fp16 split, scale 64. x & w_attn get hi+lo; w_proj hi only.
// ---------------------------------------------------------------------------
__global__ __launch_bounds__(256) void split3_f16(
    const float* __restrict__ x, _Float16* __restrict__ xh,
    _Float16* __restrict__ xl, const float* __restrict__ wa,
    _Float16* __restrict__ wah, _Float16* __restrict__ wal,
    const float* __restrict__ wp, _Float16* __restrict__ wph) {
  int i = (blockIdx.x * 256 + threadIdx.x) * 8;
  const float* src;
  _Float16 *dh, *dl = nullptr;
  int base;
  if (i < 2097152) {
    src = x; dh = xh; dl = xl; base = i;
  } else if (i < 2097152 + 3145728) {
    src = wa; dh = wah; dl = wal; base = i - 2097152;
  } else {
    src = wp; dh = wph; base = i - 5242880;
  }
  float4 a = *(const float4*)(src + base);
  float4 b = *(const float4*)(src + base + 4);
  float v[8] = {a.x, a.y, a.z, a.w, b.x, b.y, b.z, b.w};
  h8 hv, lv;
#pragma unroll
  for (int j = 0; j < 8; ++j) {
    float s = v[j] * 64.f;
    _Float16 h = (_Float16)s;
    hv[j] = h;
    lv[j] = (_Float16)(s - (float)h);
  }
  *(h8*)(dh + base) = hv;
  if (dl) *(h8*)(dl + base) = lv;
}

// fp32 octet -> fp16 hi/lo fragments (den-critical paths)
__device__ __forceinline__ void split8(float4 a, float4 b, h8& hi, h8& lo) {
  float v[8] = {a.x, a.y, a.z, a.w, b.x, b.y, b.z, b.w};
#pragma unroll
  for (int m = 0; m < 8; ++m) {
    _Float16 hh = (_Float16)v[m];
    hi[m] = hh;
    lo[m] = (_Float16)(v[m] - (float)hh);
  }
}

// ---------------------------------------------------------------------------
// Software global barrier (graph-capture-safe; no runtime-managed state).
// bar[0] = arrival counter (self-restoring to 0), bar[1] = generation.
// ---------------------------------------------------------------------------
__device__ __forceinline__ void gbar(unsigned* bar, int nb) {
  __syncthreads();
  if (threadIdx.x == 0) {
    __threadfence();  // release prior writes (agent scope: L2 writeback)
    unsigned g = __hip_atomic_load(&bar[1], __ATOMIC_RELAXED,
                                   __HIP_MEMORY_SCOPE_AGENT);
    unsigned a = __hip_atomic_fetch_add(&bar[0], 1u, __ATOMIC_ACQ_REL,
                                        __HIP_MEMORY_SCOPE_AGENT);
    if (a + 1 == (unsigned)nb) {
      __hip_atomic_store(&bar[0], 0u, __ATOMIC_RELAXED,
                         __HIP_MEMORY_SCOPE_AGENT);
      __hip_atomic_fetch_add(&bar[1], 1u, __ATOMIC_RELEASE,
                             __HIP_MEMORY_SCOPE_AGENT);
    } else {
      while (__hip_atomic_load(&bar[1], __ATOMIC_ACQUIRE,
                               __HIP_MEMORY_SCOPE_AGENT) == g)
        __builtin_amdgcn_s_sleep(32);
    }
    __threadfence();  // acquire (L1/L2 invalidate for this CU)
  }
  __syncthreads();
}

// ---------------------------------------------------------------------------
// QKV fp16 NT MFMA GEMM, BK=64, XOR-swizzled LDS. split3 for q/k blocks,
// hi*hi for v blocks (type-uniform block remap). Fused RoPE epilogue.
// NEW vs r7: k transposed store is hi-only (kTl deleted); exact per-chunk
// ksum (k-blocks) / vsum (v-blocks) computed from fp32 fv via shfl-xor quad
// reduction + LDS scratch (cs region, dead post-S2).
// ---------------------------------------------------------------------------
template <int BN, bool ROPE, bool SPLIT3>
__global__ __launch_bounds__(256) void gemm_nt_f16(
    const _Float16* __restrict__ Ah, const _Float16* __restrict__ Al,
    const _Float16* __restrict__ Bh, const _Float16* __restrict__ Bl,
    float* __restrict__ C, const float* __restrict__ cosb,
    const float* __restrict__ sinb, _Float16* __restrict__ qh_,
    _Float16* __restrict__ ql_, _Float16* __restrict__ kh_,
    _Float16* __restrict__ kl_, _Float16* __restrict__ kTh_,
    _Float16* __restrict__ vTh_, float* __restrict__ ksc_,
    float* __restrict__ vsc_, int M, int N, int K, float outscale) {
  constexpr int NJ = BN / 32;  // N-tiles per wave
  constexpr int NARR = SPLIT3 ? 2 : 1;
  constexpr int GEMM_BYTES = (64 * 64 * 2 + BN * 64 * 2) * NARR;
  constexpr int ROPE_BYTES = ROPE ? (2 * 64 * 36 * 4 + 2 * 64 * 64 * 4) : 0;
  constexpr int SMEM_BYTES = GEMM_BYTES > ROPE_BYTES ? GEMM_BYTES : ROPE_BYTES;
  __shared__ __align__(16) char smem[SMEM_BYTES];
  _Float16* sAh = (_Float16*)smem;
  _Float16* sAl = sAh + 64 * 64;                       // SPLIT3 only
  _Float16* sBh = sAh + 64 * 64 * NARR;
  _Float16* sBl = sBh + BN * 64;                       // SPLIT3 only
  const int tid = threadIdx.x;
  const int wave = tid >> 6;
  const int lane = tid & 63;
  const int bm = blockIdx.y * 64;
  const int wm = wave >> 1;          // 0..1 -> 32-row half
  const int wn = wave & 1;           // 0..1 -> BN/2-col half
  const int srow = lane >> 3;        // 0..7 staging row within chunk
  const int sblk = ((lane & 7) ^ srow) * 8;  // swizzled col block (halves)
  const int quad = lane >> 4;        // 0..3
  const int lrow = lane & 15;

  // column-block mapping (units of 64 cols)
  int btype = -1, pi = 0, cb0, cb1;
  if constexpr (ROPE) {
    btype = blockIdx.x >> 3;         // 0=q 1=k 2=v (block-uniform)
    pi = blockIdx.x & 7;             // head pair index
    cb0 = (2 * pi) * 3 + btype;
    cb1 = (2 * pi + 1) * 3 + btype;
  } else {
    cb0 = blockIdx.x * (BN / 64);
    cb1 = cb0 + 1;
  }
  const bool isV = ROPE && (btype == 2);

  f32x4 acc[2][NJ];
#pragma unroll
  for (int i = 0; i < 2; ++i)
#pragma unroll
    for (int j = 0; j < NJ; ++j) acc[i][j] = (f32x4){0.f, 0.f, 0.f, 0.f};

  for (int k0 = 0; k0 < K; k0 += 64) {
#pragma unroll
    for (int it = 0; it < 2; ++it) {
      const int ch = wave + it * 4;  // 0..7
      const int row = ch * 8 + srow;
      const _Float16* ga = Ah + (size_t)(bm + row) * K + k0 + sblk;
      __builtin_amdgcn_global_load_lds(
          (const __attribute__((address_space(1))) void*)ga,
          (__attribute__((address_space(3))) void*)(sAh + ch * 512), 16, 0, 0);
      if constexpr (SPLIT3) {
        if (!isV) {
          const _Float16* gb = Al + (size_t)(bm + row) * K + k0 + sblk;
          __builtin_amdgcn_global_load_lds(
              (const __attribute__((address_space(1))) void*)gb,
              (__attribute__((address_space(3))) void*)(sAl + ch * 512), 16, 0,
              0);
        }
      }
    }
#pragma unroll
    for (int it = 0; it < BN / 32; ++it) {
      const int ch = wave + it * 4;  // 0..BN/8-1
      const int lr = ch * 8 + srow;  // 0..BN-1 local col-row
      const int grow = ((lr < 64) ? cb0 : cb1) * 64 + (lr & 63);
      const _Float16* ga = Bh + (size_t)grow * K + k0 + sblk;
      __builtin_amdgcn_global_load_lds(
          (const __attribute__((address_space(1))) void*)ga,
          (__attribute__((address_space(3))) void*)(sBh + ch * 512), 16, 0, 0);
      if constexpr (SPLIT3) {
        if (!isV) {
          const _Float16* gb = Bl + (size_t)grow * K + k0 + sblk;
          __builtin_amdgcn_global_load_lds(
              (const __attribute__((address_space(1))) void*)gb,
              (__attribute__((address_space(3))) void*)(sBl + ch * 512), 16, 0,
              0);
        }
      }
    }
    __syncthreads();
    if (SPLIT3 && !isV) {
#pragma unroll
      for (int kk = 0; kk < 2; ++kk) {
        h8 ah[2], al[2], bh[NJ], bl[NJ];
#pragma unroll
        for (int i = 0; i < 2; ++i) {
          const int row = wm * 32 + i * 16 + lrow;
          const int ra = row * 64 + (((kk * 4 + quad) ^ (row & 7)) * 8);
          ah[i] = *(const h8*)&sAh[ra];
          al[i] = *(const h8*)&sAl[ra];
        }
#pragma unroll
        for (int j = 0; j < NJ; ++j) {
          const int row = wn * (BN / 2) + j * 16 + lrow;
          const int rb = row * 64 + (((kk * 4 + quad) ^ (row & 7)) * 8);
          bh[j] = *(const h8*)&sBh[rb];
          bl[j] = *(const h8*)&sBl[rb];
        }
#pragma unroll
        for (int i = 0; i < 2; ++i)
#pragma unroll
          for (int j = 0; j < NJ; ++j) {
            acc[i][j] = __builtin_amdgcn_mfma_f32_16x16x32_f16(
                ah[i], bh[j], acc[i][j], 0, 0, 0);
            acc[i][j] = __builtin_amdgcn_mfma_f32_16x16x32_f16(
                ah[i], bl[j], acc[i][j], 0, 0, 0);
            acc[i][j] = __builtin_amdgcn_mfma_f32_16x16x32_f16(
                al[i], bh[j], acc[i][j], 0, 0, 0);
          }
      }
    } else {
#pragma unroll
      for (int kk = 0; kk < 2; ++kk) {
        h8 ah[2], bh[NJ];
#pragma unroll
        for (int i = 0; i < 2; ++i) {
          const int row = wm * 32 + i * 16 + lrow;
          const int ra = row * 64 + (((kk * 4 + quad) ^ (row & 7)) * 8);
          ah[i] = *(const h8*)&sAh[ra];
        }
#pragma unroll
        for (int j = 0; j < NJ; ++j) {
          const int row = wn * (BN / 2) + j * 16 + lrow;
          const int rb = row * 64 + (((kk * 4 + quad) ^ (row & 7)) * 8);
          bh[j] = *(const h8*)&sBh[rb];
        }
#pragma unroll
        for (int i = 0; i < 2; ++i)
#pragma unroll
          for (int j = 0; j < NJ; ++j)
            acc[i][j] = __builtin_amdgcn_mfma_f32_16x16x32_f16(
                ah[i], bh[j], acc[i][j], 0, 0, 0);
      }
    }
    __syncthreads();
  }
  // epilogue: C/D layout col=lane&15, row=quad*4+reg
  if constexpr (!ROPE) {
#pragma unroll
    for (int i = 0; i < 2; ++i) {
      const int rbase = bm + wm * 32 + i * 16 + quad * 4;
#pragma unroll
      for (int j = 0; j < NJ; ++j) {
        const int col = blockIdx.x * BN + wn * (BN / 2) + j * 16 + lrow;
#pragma unroll
        for (int r = 0; r < 4; ++r)
          C[(size_t)(rbase + r) * N + col] = acc[i][j][r] * outscale;
      }
    }
  } else {
    float* cs = (float*)smem;        // [64][36] cos (9 KB); scratch post-S2
    float* sn = cs + 2304;           // [64][36] sin (9 KB)
    float* bounce = sn + 2304;       // 2 x 4096 fp32 = 32 KB
    if (btype < 2) {
      const int el = tid * 8;        // 2048 payload floats, 8 per thread
      const int t = el >> 5, d0 = el & 31;
      const float* gc = &cosb[(size_t)(bm + t) * D_DIM + d0];
      const float* gs = &sinb[(size_t)(bm + t) * D_DIM + d0];
      *(float4*)&cs[t * 36 + d0] = *(const float4*)gc;
      *(float4*)&cs[t * 36 + d0 + 4] = *(const float4*)(gc + 4);
      *(float4*)&sn[t * 36 + d0] = *(const float4*)gs;
      *(float4*)&sn[t * 36 + d0 + 4] = *(const float4*)(gs + 4);
    }
    __syncthreads();                 // S1
    const int head = 2 * pi + wn;    // each wn half = one head, same type
    const size_t hb = (size_t)head * T_LEN * D_DIM;
    // final fp32 values (rope applied for q/k), fv[i][reg][j]
    float fv[2][4][4];
#pragma unroll
    for (int i = 0; i < 2; ++i)
#pragma unroll
      for (int r = 0; r < 4; ++r) {
        const int tloc = wm * 32 + i * 16 + quad * 4 + r;
#pragma unroll
        for (int j = 0; j < 4; ++j) {
          const int d32 = (j & 1) * 16 + lrow;   // d mod 32
          float val = acc[i][j][r] * outscale;
          if (btype < 2) {
            float rotv =
                ((j < 2) ? -acc[i][j + 2][r] : acc[i][j - 2][r]) * outscale;
            val = val * cs[tloc * 36 + d32] + rotv * sn[tloc * 36 + d32];
          }
          fv[i][r][j] = val;
        }
      }
    // direct (t,d) fp16 hi/lo stores for q and k (den-critical: keep split)
    if (btype < 2) {
      _Float16* dh = (btype == 0 ? qh_ : kh_) + hb;
      _Float16* dl = (btype == 0 ? ql_ : kl_) + hb;
#pragma unroll
      for (int i = 0; i < 2; ++i)
#pragma unroll
        for (int r = 0; r < 4; ++r) {
          const size_t trow =
              (size_t)(bm + wm * 32 + i * 16 + quad * 4 + r) * D_DIM;
#pragma unroll
          for (int j = 0; j < 4; ++j) {
            const int d = j * 16 + lrow;
            float f = fv[i][r][j];
            _Float16 hh = (_Float16)f;
            dh[trow + d] = hh;
            dl[trow + d] = (_Float16)(f - (float)hh);
          }
        }
    }
    // k/v blocks: hi-only transposed store + exact per-chunk column sums
    if (btype >= 1) {
      _Float16* th = (btype == 1 ? kTh_ : vTh_) + hb;
      float* myb = bounce + wn * 4096;
#pragma unroll
      for (int i = 0; i < 2; ++i)
#pragma unroll
        for (int r = 0; r < 4; ++r) {
          const int tloc = wm * 32 + i * 16 + quad * 4 + r;
#pragma unroll
          for (int j = 0; j < 4; ++j) {
            const int d = j * 16 + lrow;
            myb[tloc * 64 + (d ^ tloc)] = fv[i][r][j];
          }
        }
      // per-thread chunk-sum partials over this thread's 8 rows
      float ps[4];
#pragma unroll
      for (int j = 0; j < 4; ++j) {
        ps[j] = 0.f;
#pragma unroll
        for (int i = 0; i < 2; ++i)
#pragma unroll
          for (int r = 0; r < 4; ++r) ps[j] += fv[i][r][j];
        // reduce across quads (lanes lrow, +16, +32, +48)
        ps[j] += __shfl_xor(ps[j], 16);
        ps[j] += __shfl_xor(ps[j], 32);
      }
      __syncthreads();               // S2
      // bounce reads + hi-only transposed global stores
      {
        const int lt = wm * 64 + lane;   // 0..127 over the 2 same-wn waves
        const int e = lt >> 1;           // output row (dim)
        const int tg0 = (lt & 1) * 32;   // 32-t half
#pragma unroll
        for (int s8 = 0; s8 < 4; ++s8) {
          h8 hv;
#pragma unroll
          for (int s = 0; s < 8; ++s) {
            const int t = tg0 + s8 * 8 + s;
            hv[s] = (_Float16)myb[t * 64 + (e ^ t)];
          }
          *(h8*)&th[(size_t)e * T_LEN + bm + tg0 + s8 * 8] = hv;
        }
      }
      // scratch (cs region, dead after S2): wave partials per wn/wm
      if (quad == 0) {
#pragma unroll
        for (int j = 0; j < 4; ++j)
          cs[(wn * 2 + wm) * 64 + j * 16 + lrow] = ps[j];
      }
      __syncthreads();               // S3
      if (wm == 0 && quad == 0) {
        float* dst = (btype == 1 ? ksc_ : vsc_);
        const int c = bm >> 6;
#pragma unroll
        for (int j = 0; j < 4; ++j) {
          const int d = j * 16 + lrow;
          float s = cs[(wn * 2) * 64 + d] + cs[(wn * 2 + 1) * 64 + d];
          dst[((size_t)head * NC + c) * 64 + d] = s;
        }
      }
    }
  }
}

// ---------------------------------------------------------------------------
// Fused middle (software-barrier, graph-safe): phase1 chunk KV^T product ->
// gbar -> phase2 exclusive prefix scans -> gbar -> phase3 MFMA attention.
// 512 blocks x 256 threads, 16 KB LDS, co-residency guaranteed (2 blk/CU).
// ---------------------------------------------------------------------------
__global__ __launch_bounds__(256, 2) void middle_fused(
    const _Float16* __restrict__ kTh, const _Float16* __restrict__ vTh,
    float* __restrict__ kvchunk, const float* __restrict__ kschunk,
    const float* __restrict__ vschunk, _Float16* __restrict__ kvph,
    float* __restrict__ kspref, float* __restrict__ vspref,
    const _Float16* __restrict__ qh, const _Float16* __restrict__ ql,
    const _Float16* __restrict__ kh, const _Float16* __restrict__ kl,
    _Float16* __restrict__ yh, unsigned* bar) {
  __shared__ __align__(16) char sm[16384];
  const int tid = threadIdx.x;
  const int bid = blockIdx.x;  // 0..511
  const int nb = gridDim.x;
  const int wave = tid >> 6, lane = tid & 63;
  const int quad = lane >> 4, lrow = lane & 15;
  const f32x4 z4 = {0.f, 0.f, 0.f, 0.f};

  // ===== phase 1: per-(head,chunk) KV^T product (hi*hi) =====
  {
    const int h = bid / NC, c = bid % NC;
    const size_t hbT = (size_t)h * D_DIM * T_LEN;
    const int tb = c * L_CHK;
    h8 avh[2];
    {
      const _Float16* pa =
          vTh + hbT + (size_t)(wave * 16 + lrow) * T_LEN + tb + quad * 8;
      avh[0] = *(const h8*)pa;
      avh[1] = *(const h8*)(pa + 32);
    }
    f32x4 accv[4];
#pragma unroll
    for (int dt = 0; dt < 4; ++dt) accv[dt] = z4;
#pragma unroll
    for (int dt = 0; dt < 4; ++dt) {
      const _Float16* pb =
          kTh + hbT + (size_t)(dt * 16 + lrow) * T_LEN + tb + quad * 8;
#pragma unroll
      for (int ks = 0; ks < 2; ++ks) {
        h8 bh = *(const h8*)(pb + ks * 32);
        accv[dt] = __builtin_amdgcn_mfma_f32_16x16x32_f16(avh[ks], bh,
                                                          accv[dt], 0, 0, 0);
      }
    }
    float* ob = kvchunk + (size_t)bid * (D_DIM * D_DIM);
#pragma unroll
    for (int dt = 0; dt < 4; ++dt)
#pragma unroll
      for (int r = 0; r < 4; ++r)
        ob[(wave * 16 + quad * 4 + r) * D_DIM + dt * 16 + lrow] = accv[dt][r];
  }
  gbar(bar, nb);

  // ===== phase 2: exclusive prefix scans (blocks 0..259) =====
  if (bid < 256) {
    int gid = bid * 256 + tid;  // h*4096 + de
    int h = gid >> 12;
    int de = gid & 4095;
    float vals[NC];
#pragma unroll
    for (int c = 0; c < NC; ++c)
      vals[c] = kvchunk[((size_t)(h * NC + c) << 12) + de];
    float run = 0.f;
#pragma unroll
    for (int c = 0; c < NC; ++c) {
      kvph[((size_t)(h * NC + c) << 12) + de] = (_Float16)run;
      run += vals[c];
    }
  } else if (bid < 260) {
    int gid = (bid - 256) * 256 + tid;  // h*64 + d (total 1024)
    int h = gid >> 6, d = gid & 63;
    float kv_[NC], vv_[NC];
#pragma unroll
    for (int c = 0; c < NC; ++c) {
      size_t idx = (size_t)(h * NC + c) * 64 + d;
      kv_[c] = kschunk[idx];
      vv_[c] = vschunk[idx];
    }
    float rk = 0.f, rv = 0.f;
#pragma unroll
    for (int c = 0; c < NC; ++c) {
      size_t idx = (size_t)(h * NC + c) * 64 + d;
      kspref[idx] = rk;
      vspref[idx] = rv;
      rk += kv_[c];
      rv += vv_[c];
    }
  }
  gbar(bar, nb);

  // ===== phase 3: MFMA attention output =====
  {
    const int h = bid / NC, c = bid % NC;
    const size_t hb = (size_t)h * T_LEN * D_DIM;   // (t,d) arrays
    const size_t hbT = (size_t)h * D_DIM * T_LEN;  // (e,t) arrays
    const int t0 = c * L_CHK;
    _Float16* sS = (_Float16*)sm;  // [2 planes][4 waves][16*64]
    h8 aqh[2], aql[2];
    {
      const _Float16* pq =
          qh + hb + (size_t)(t0 + wave * 16 + lrow) * D_DIM + quad * 8;
      const _Float16* pql =
          ql + hb + (size_t)(t0 + wave * 16 + lrow) * D_DIM + quad * 8;
      aqh[0] = *(const h8*)pq;
      aqh[1] = *(const h8*)(pq + 32);
      aql[0] = *(const h8*)pql;
      aql[1] = *(const h8*)(pql + 32);
    }
    f32x4 sacc[4];
#pragma unroll
    for (int jt = 0; jt < 4; ++jt) sacc[jt] = z4;
#pragma unroll
    for (int jt = 0; jt < 4; ++jt) {
      const _Float16* pk =
          kh + hb + (size_t)(t0 + jt * 16 + lrow) * D_DIM + quad * 8;
      const _Float16* pkl =
          kl + hb + (size_t)(t0 + jt * 16 + lrow) * D_DIM + quad * 8;
#pragma unroll
      for (int ks = 0; ks < 2; ++ks) {
        h8 bh = *(const h8*)(pk + ks * 32);
        h8 bl = *(const h8*)(pkl + ks * 32);
        sacc[jt] = __builtin_amdgcn_mfma_f32_16x16x32_f16(aqh[ks], bh,
                                                          sacc[jt], 0, 0, 0);
        sacc[jt] = __builtin_amdgcn_mfma_f32_16x16x32_f16(aqh[ks], bl,
                                                          sacc[jt], 0, 0, 0);
        sacc[jt] = __builtin_amdgcn_mfma_f32_16x16x32_f16(aql[ks], bh,
                                                          sacc[jt], 0, 0, 0);
      }
    }
    _Float16* shp = sS + wave * 1024;
    _Float16* slp = sS + (4 + wave) * 1024;
#pragma unroll
    for (int jt = 0; jt < 4; ++jt)
#pragma unroll
      for (int r = 0; r < 4; ++r) {
        const int row = quad * 4 + r;          // band-local row
        const int j = jt * 16 + lrow;          // chunk-local col
        const int rglob = wave * 16 + row;
        float s = (j <= rglob) ? (sacc[jt][r] + 1.f) : 0.f;
        _Float16 hh = (_Float16)s;
        const int adr = row * 64 + ((((j >> 3) ^ (row & 7)) << 3) | (j & 7));
        shp[adr] = hh;
        slp[adr] = (_Float16)(s - (float)hh);
      }
    h8 ash[2], asl[2];
#pragma unroll
    for (int ks = 0; ks < 2; ++ks) {
      const int adr = lrow * 64 + (((ks * 4 + quad) ^ (lrow & 7)) << 3);
      ash[ks] = *(const h8*)&shp[adr];
      asl[ks] = *(const h8*)&slp[adr];
    }
    h8 ones;
#pragma unroll
    for (int m = 0; m < 8; ++m) ones[m] = (_Float16)1.0f;
    f32x4 rs = z4;
#pragma unroll
    for (int ks = 0; ks < 2; ++ks) {
      rs = __builtin_amdgcn_mfma_f32_16x16x32_f16(ash[ks], ones, rs, 0, 0, 0);
      rs = __builtin_amdgcn_mfma_f32_16x16x32_f16(asl[ks], ones, rs, 0, 0, 0);
    }
    f32x4 oacc[4];
#pragma unroll
    for (int et = 0; et < 4; ++et) oacc[et] = z4;
#pragma unroll
    for (int et = 0; et < 4; ++et) {
      const _Float16* pv =
          vTh + hbT + (size_t)(et * 16 + lrow) * T_LEN + t0 + quad * 8;
#pragma unroll
      for (int ks = 0; ks < 2; ++ks) {
        h8 bh = *(const h8*)(pv + ks * 32);
        oacc[et] = __builtin_amdgcn_mfma_f32_16x16x32_f16(ash[ks], bh,
                                                          oacc[et], 0, 0, 0);
        oacc[et] = __builtin_amdgcn_mfma_f32_16x16x32_f16(asl[ks], bh,
                                                          oacc[et], 0, 0, 0);
      }
    }
    const _Float16* kvp = kvph + ((size_t)bid << 12);
#pragma unroll
    for (int et = 0; et < 4; ++et) {
#pragma unroll
      for (int ks = 0; ks < 2; ++ks) {
        h8 bh =
            *(const h8*)&kvp[(et * 16 + lrow) * D_DIM + ks * 32 + quad * 8];
        oacc[et] = __builtin_amdgcn_mfma_f32_16x16x32_f16(aqh[ks], bh,
                                                          oacc[et], 0, 0, 0);
      }
    }
    const float* ksp = kspref + (size_t)bid * D_DIM;
    f32x4 kacc = z4;
#pragma unroll
    for (int ks = 0; ks < 2; ++ks) {
      const float* pb = ksp + ks * 32 + quad * 8;
      float4 b0 = *(const float4*)pb;
      float4 b1 = *(const float4*)(pb + 4);
      h8 bh, bl;
      split8(b0, b1, bh, bl);
      kacc = __builtin_amdgcn_mfma_f32_16x16x32_f16(aqh[ks], bh, kacc, 0, 0,
                                                    0);
      kacc = __builtin_amdgcn_mfma_f32_16x16x32_f16(aqh[ks], bl, kacc, 0, 0,
                                                    0);
      kacc = __builtin_amdgcn_mfma_f32_16x16x32_f16(aql[ks], bh, kacc, 0, 0,
                                                    0);
    }
    const float* vsp = vspref + (size_t)bid * D_DIM;
#pragma unroll
    for (int r = 0; r < 4; ++r) {
      const int row = wave * 16 + quad * 4 + r;  // chunk-local t
      const float den = (float)(c * L_CHK) + rs[r] + kacc[r];
      const float inv = 1.f / den;
      const size_t ybase = (size_t)(t0 + row) * (H_NUM * D_DIM) + h * D_DIM;
#pragma unroll
      for (int et = 0; et < 4; ++et) {
        const int e = et * 16 + lrow;
        const float num = oacc[et][r] + vsp[e];
        yh[ybase + e] = (_Float16)(num * inv);
      }
    }
  }
}

// ---------------------------------------------------------------------------
extern "C" void kernel_launch(void* const* d_in, const int* in_sizes, int n_in,
                              void* d_out, int out_size, void* d_ws,
                              size_t ws_size, hipStream_t stream) {
  const float* x = (const float*)d_in[0];       // (1,2048,1024)
  const float* w_attn = (const float*)d_in[1];  // (3072,1024)
  const float* w_proj = (const float*)d_in[2];  // (1024,1024)
  const float* cosb = (const float*)d_in[3];    // (2048,64)
  const float* sinb = (const float*)d_in[4];    // (2048,64)
  float* out = (float*)d_out;                   // (2048,1024)

  char* ws = (char*)d_ws;
  const size_t MB = 1048576;
  // 0..8MB: kvchunk fp32; 8..12MB: kvph fp16 prefix
  float* kvchunk = (float*)ws;
  _Float16* kvph = (_Float16*)(ws + 8 * MB);
  // 12..16MB hole: barrier + chunk sum vectors (written by QKV epilogue!)
  unsigned* bar = (unsigned*)(ws + 12 * MB);
  float* kschunk = (float*)(ws + 12 * MB + 4096);
  float* vschunk = (float*)(ws + 12 * MB + 4096 + 131072);
  float* kspref = (float*)(ws + 12 * MB + 4096 + 262144);
  float* vspref = (float*)(ws + 12 * MB + 4096 + 393216);
  // 16..44MB: fp16 q,k hi/lo (t,d); kT hi, vT hi (d/e, t)
  _Float16* qh = (_Float16*)(ws + 16 * MB);
  _Float16* ql = (_Float16*)(ws + 20 * MB);
  _Float16* kh = (_Float16*)(ws + 24 * MB);
  _Float16* kl = (_Float16*)(ws + 28 * MB);
  _Float16* kTh = (_Float16*)(ws + 32 * MB);
  _Float16* vTh = (_Float16*)(ws + 40 * MB);
  // 48..56MB: xh/xl (live split->QKV GEMM); then yh.
  _Float16* xh = (_Float16*)(ws + 48 * MB);
  _Float16* xl = (_Float16*)(ws + 52 * MB);
  _Float16* yh = (_Float16*)(ws + 48 * MB);
  // 56..68MB: wah/wal (live split->QKV GEMM).
  _Float16* wah = (_Float16*)(ws + 56 * MB);
  _Float16* wal = (_Float16*)(ws + 62 * MB);
  // 68..70MB: wph (live whole call).
  _Float16* wph = (_Float16*)(ws + 68 * MB);

  // barrier state init (graph memset node; cnt self-restores to 0)
  hipMemsetAsync(bar, 0, 16, stream);

  // 0) fused splits (scale 64, undone in epilogues); w_proj hi-only
  split3_f16<<<3072, 256, 0, stream>>>(x, xh, xl, w_attn, wah, wal, w_proj,
                                       wph);

  // 1) qkv GEMM (type-uniform blocks; v hi*hi) + RoPE + exact ksum/vsum
  {
    dim3 grid(QKV_N / 128, T_LEN / 64);   // 24 x 32 = 768 blocks
    gemm_nt_f16<128, true, true><<<grid, 256, 0, stream>>>(
        xh, xl, wah, wal, nullptr, cosb, sinb, qh, ql, kh, kl, kTh, vTh,
        kschunk, vschunk, T_LEN, QKV_N, C_DIM, 1.f / 4096.f);
  }
  // 2) fused middle: chunk product -> scans -> attention (software barrier)
  middle_fused<<<512, 256, 0, stream>>>(kTh, vTh, kvchunk, kschunk, vschunk,
                                        kvph, kspref, vspref, qh, ql, kh, kl,
                                        yh, bar);
  // 3) out = y @ w_proj^T (plain fp16, 64x64 tiles, 512 blocks): 2^-6
  {
    dim3 grid(C_DIM / 64, T_LEN / 64);    // 16 x 32 = 512 blocks
    gemm_nt_f16<64, false, false><<<grid, 256, 0, stream>>>(
        yh, nullptr, wph, nullptr, out, nullptr, nullptr, nullptr, nullptr,
        nullptr, nullptr, nullptr, nullptr, nullptr, nullptr, T_LEN, C_DIM,
        C_DIM, 1.f / 64.f);
  }
}

// Round 10
// 150.943 us; speedup vs baseline: 2.0971x; 2.0971x over previous
//
#include <hip/hip_runtime.h>

// Problem constants (B=1)
#define T_LEN 2048
#define C_DIM 1024
#define H_NUM 16
#define D_DIM 64
#define QKV_N (3 * H_NUM * D_DIM)   // 3072
#define L_CHK 64
#define NC (T_LEN / L_CHK)          // 32

typedef _Float16 h8 __attribute__((ext_vector_type(8)));
typedef _Float16 h4 __attribute__((ext_vector_type(4)));
typedef float f32x4 __attribute__((ext_vector_type(4)));

// ---------------------------------------------------------------------------
// Fused fp32 -> fp16 split, scale 64. x & w_attn get hi+lo; w_proj hi only.
// ---------------------------------------------------------------------------
__global__ __launch_bounds__(256) void split3_f16(
    const float* __restrict__ x, _Float16* __restrict__ xh,
    _Float16* __restrict__ xl, const float* __restrict__ wa,
    _Float16* __restrict__ wah, _Float16* __restrict__ wal,
    const float* __restrict__ wp, _Float16* __restrict__ wph) {
  int i = (blockIdx.x * 256 + threadIdx.x) * 8;
  const float* src;
  _Float16 *dh, *dl = nullptr;
  int base;
  if (i < 2097152) {
    src = x; dh = xh; dl = xl; base = i;
  } else if (i < 2097152 + 3145728) {
    src = wa; dh = wah; dl = wal; base = i - 2097152;
  } else {
    src = wp; dh = wph; base = i - 5242880;
  }
  float4 a = *(const float4*)(src + base);
  float4 b = *(const float4*)(src + base + 4);
  float v[8] = {a.x, a.y, a.z, a.w, b.x, b.y, b.z, b.w};
  h8 hv, lv;
#pragma unroll
  for (int j = 0; j < 8; ++j) {
    float s = v[j] * 64.f;
    _Float16 h = (_Float16)s;
    hv[j] = h;
    lv[j] = (_Float16)(s - (float)h);
  }
  *(h8*)(dh + base) = hv;
  if (dl) *(h8*)(dl + base) = lv;
}

// fp32 octet -> fp16 hi/lo fragments (den-critical paths)
__device__ __forceinline__ void split8(float4 a, float4 b, h8& hi, h8& lo) {
  float v[8] = {a.x, a.y, a.z, a.w, b.x, b.y, b.z, b.w};
#pragma unroll
  for (int m = 0; m < 8; ++m) {
    _Float16 hh = (_Float16)v[m];
    hi[m] = hh;
    lo[m] = (_Float16)(v[m] - (float)hh);
  }
}

// ---------------------------------------------------------------------------
// QKV fp16 NT MFMA GEMM, BK=64, XOR-swizzled LDS. split3 for q/k blocks,
// hi*hi for v blocks (type-uniform block remap). Fused RoPE epilogue.
// k transposed store is hi-only (kTl deleted); exact per-chunk ksum
// (k-blocks) / vsum (v-blocks) computed from fp32 fv via shfl-xor quad
// reduction + LDS scratch. All verified in round 9 (absmax 1.0).
// ---------------------------------------------------------------------------
template <int BN, bool ROPE, bool SPLIT3>
__global__ __launch_bounds__(256) void gemm_nt_f16(
    const _Float16* __restrict__ Ah, const _Float16* __restrict__ Al,
    const _Float16* __restrict__ Bh, const _Float16* __restrict__ Bl,
    float* __restrict__ C, const float* __restrict__ cosb,
    const float* __restrict__ sinb, _Float16* __restrict__ qh_,
    _Float16* __restrict__ ql_, _Float16* __restrict__ kh_,
    _Float16* __restrict__ kl_, _Float16* __restrict__ kTh_,
    _Float16* __restrict__ vTh_, float* __restrict__ ksc_,
    float* __restrict__ vsc_, int M, int N, int K, float outscale) {
  constexpr int NJ = BN / 32;  // N-tiles per wave
  constexpr int NARR = SPLIT3 ? 2 : 1;
  constexpr int GEMM_BYTES = (64 * 64 * 2 + BN * 64 * 2) * NARR;
  constexpr int ROPE_BYTES = ROPE ? (2 * 64 * 36 * 4 + 2 * 64 * 64 * 4) : 0;
  constexpr int SMEM_BYTES = GEMM_BYTES > ROPE_BYTES ? GEMM_BYTES : ROPE_BYTES;
  __shared__ __align__(16) char smem[SMEM_BYTES];
  _Float16* sAh = (_Float16*)smem;
  _Float16* sAl = sAh + 64 * 64;                       // SPLIT3 only
  _Float16* sBh = sAh + 64 * 64 * NARR;
  _Float16* sBl = sBh + BN * 64;                       // SPLIT3 only
  const int tid = threadIdx.x;
  const int wave = tid >> 6;
  const int lane = tid & 63;
  const int bm = blockIdx.y * 64;
  const int wm = wave >> 1;          // 0..1 -> 32-row half
  const int wn = wave & 1;           // 0..1 -> BN/2-col half
  const int srow = lane >> 3;        // 0..7 staging row within chunk
  const int sblk = ((lane & 7) ^ srow) * 8;  // swizzled col block (halves)
  const int quad = lane >> 4;        // 0..3
  const int lrow = lane & 15;

  // column-block mapping (units of 64 cols)
  int btype = -1, pi = 0, cb0, cb1;
  if constexpr (ROPE) {
    btype = blockIdx.x >> 3;         // 0=q 1=k 2=v (block-uniform)
    pi = blockIdx.x & 7;             // head pair index
    cb0 = (2 * pi) * 3 + btype;
    cb1 = (2 * pi + 1) * 3 + btype;
  } else {
    cb0 = blockIdx.x * (BN / 64);
    cb1 = cb0 + 1;
  }
  const bool isV = ROPE && (btype == 2);

  f32x4 acc[2][NJ];
#pragma unroll
  for (int i = 0; i < 2; ++i)
#pragma unroll
    for (int j = 0; j < NJ; ++j) acc[i][j] = (f32x4){0.f, 0.f, 0.f, 0.f};

  for (int k0 = 0; k0 < K; k0 += 64) {
#pragma unroll
    for (int it = 0; it < 2; ++it) {
      const int ch = wave + it * 4;  // 0..7
      const int row = ch * 8 + srow;
      const _Float16* ga = Ah + (size_t)(bm + row) * K + k0 + sblk;
      __builtin_amdgcn_global_load_lds(
          (const __attribute__((address_space(1))) void*)ga,
          (__attribute__((address_space(3))) void*)(sAh + ch * 512), 16, 0, 0);
      if constexpr (SPLIT3) {
        if (!isV) {
          const _Float16* gb = Al + (size_t)(bm + row) * K + k0 + sblk;
          __builtin_amdgcn_global_load_lds(
              (const __attribute__((address_space(1))) void*)gb,
              (__attribute__((address_space(3))) void*)(sAl + ch * 512), 16, 0,
              0);
        }
      }
    }
#pragma unroll
    for (int it = 0; it < BN / 32; ++it) {
      const int ch = wave + it * 4;  // 0..BN/8-1
      const int lr = ch * 8 + srow;  // 0..BN-1 local col-row
      const int grow = ((lr < 64) ? cb0 : cb1) * 64 + (lr & 63);
      const _Float16* ga = Bh + (size_t)grow * K + k0 + sblk;
      __builtin_amdgcn_global_load_lds(
          (const __attribute__((address_space(1))) void*)ga,
          (__attribute__((address_space(3))) void*)(sBh + ch * 512), 16, 0, 0);
      if constexpr (SPLIT3) {
        if (!isV) {
          const _Float16* gb = Bl + (size_t)grow * K + k0 + sblk;
          __builtin_amdgcn_global_load_lds(
              (const __attribute__((address_space(1))) void*)gb,
              (__attribute__((address_space(3))) void*)(sBl + ch * 512), 16, 0,
              0);
        }
      }
    }
    __syncthreads();
    if (SPLIT3 && !isV) {
#pragma unroll
      for (int kk = 0; kk < 2; ++kk) {
        h8 ah[2], al[2], bh[NJ], bl[NJ];
#pragma unroll
        for (int i = 0; i < 2; ++i) {
          const int row = wm * 32 + i * 16 + lrow;
          const int ra = row * 64 + (((kk * 4 + quad) ^ (row & 7)) * 8);
          ah[i] = *(const h8*)&sAh[ra];
          al[i] = *(const h8*)&sAl[ra];
        }
#pragma unroll
        for (int j = 0; j < NJ; ++j) {
          const int row = wn * (BN / 2) + j * 16 + lrow;
          const int rb = row * 64 + (((kk * 4 + quad) ^ (row & 7)) * 8);
          bh[j] = *(const h8*)&sBh[rb];
          bl[j] = *(const h8*)&sBl[rb];
        }
#pragma unroll
        for (int i = 0; i < 2; ++i)
#pragma unroll
          for (int j = 0; j < NJ; ++j) {
            acc[i][j] = __builtin_amdgcn_mfma_f32_16x16x32_f16(
                ah[i], bh[j], acc[i][j], 0, 0, 0);
            acc[i][j] = __builtin_amdgcn_mfma_f32_16x16x32_f16(
                ah[i], bl[j], acc[i][j], 0, 0, 0);
            acc[i][j] = __builtin_amdgcn_mfma_f32_16x16x32_f16(
                al[i], bh[j], acc[i][j], 0, 0, 0);
          }
      }
    } else {
#pragma unroll
      for (int kk = 0; kk < 2; ++kk) {
        h8 ah[2], bh[NJ];
#pragma unroll
        for (int i = 0; i < 2; ++i) {
          const int row = wm * 32 + i * 16 + lrow;
          const int ra = row * 64 + (((kk * 4 + quad) ^ (row & 7)) * 8);
          ah[i] = *(const h8*)&sAh[ra];
        }
#pragma unroll
        for (int j = 0; j < NJ; ++j) {
          const int row = wn * (BN / 2) + j * 16 + lrow;
          const int rb = row * 64 + (((kk * 4 + quad) ^ (row & 7)) * 8);
          bh[j] = *(const h8*)&sBh[rb];
        }
#pragma unroll
        for (int i = 0; i < 2; ++i)
#pragma unroll
          for (int j = 0; j < NJ; ++j)
            acc[i][j] = __builtin_amdgcn_mfma_f32_16x16x32_f16(
                ah[i], bh[j], acc[i][j], 0, 0, 0);
      }
    }
    __syncthreads();
  }
  // epilogue: C/D layout col=lane&15, row=quad*4+reg
  if constexpr (!ROPE) {
#pragma unroll
    for (int i = 0; i < 2; ++i) {
      const int rbase = bm + wm * 32 + i * 16 + quad * 4;
#pragma unroll
      for (int j = 0; j < NJ; ++j) {
        const int col = blockIdx.x * BN + wn * (BN / 2) + j * 16 + lrow;
#pragma unroll
        for (int r = 0; r < 4; ++r)
          C[(size_t)(rbase + r) * N + col] = acc[i][j][r] * outscale;
      }
    }
  } else {
    float* cs = (float*)smem;        // [64][36] cos (9 KB); scratch post-S2
    float* sn = cs + 2304;           // [64][36] sin (9 KB)
    float* bounce = sn + 2304;       // 2 x 4096 fp32 = 32 KB
    if (btype < 2) {
      const int el = tid * 8;        // 2048 payload floats, 8 per thread
      const int t = el >> 5, d0 = el & 31;
      const float* gc = &cosb[(size_t)(bm + t) * D_DIM + d0];
      const float* gs = &sinb[(size_t)(bm + t) * D_DIM + d0];
      *(float4*)&cs[t * 36 + d0] = *(const float4*)gc;
      *(float4*)&cs[t * 36 + d0 + 4] = *(const float4*)(gc + 4);
      *(float4*)&sn[t * 36 + d0] = *(const float4*)gs;
      *(float4*)&sn[t * 36 + d0 + 4] = *(const float4*)(gs + 4);
    }
    __syncthreads();                 // S1
    const int head = 2 * pi + wn;    // each wn half = one head, same type
    const size_t hb = (size_t)head * T_LEN * D_DIM;
    // final fp32 values (rope applied for q/k), fv[i][reg][j]
    float fv[2][4][4];
#pragma unroll
    for (int i = 0; i < 2; ++i)
#pragma unroll
      for (int r = 0; r < 4; ++r) {
        const int tloc = wm * 32 + i * 16 + quad * 4 + r;
#pragma unroll
        for (int j = 0; j < 4; ++j) {
          const int d32 = (j & 1) * 16 + lrow;   // d mod 32
          float val = acc[i][j][r] * outscale;
          if (btype < 2) {
            float rotv =
                ((j < 2) ? -acc[i][j + 2][r] : acc[i][j - 2][r]) * outscale;
            val = val * cs[tloc * 36 + d32] + rotv * sn[tloc * 36 + d32];
          }
          fv[i][r][j] = val;
        }
      }
    // direct (t,d) fp16 hi/lo stores for q and k (den-critical: keep split)
    if (btype < 2) {
      _Float16* dh = (btype == 0 ? qh_ : kh_) + hb;
      _Float16* dl = (btype == 0 ? ql_ : kl_) + hb;
#pragma unroll
      for (int i = 0; i < 2; ++i)
#pragma unroll
        for (int r = 0; r < 4; ++r) {
          const size_t trow =
              (size_t)(bm + wm * 32 + i * 16 + quad * 4 + r) * D_DIM;
#pragma unroll
          for (int j = 0; j < 4; ++j) {
            const int d = j * 16 + lrow;
            float f = fv[i][r][j];
            _Float16 hh = (_Float16)f;
            dh[trow + d] = hh;
            dl[trow + d] = (_Float16)(f - (float)hh);
          }
        }
    }
    // k/v blocks: hi-only transposed store + exact per-chunk column sums
    if (btype >= 1) {
      _Float16* th = (btype == 1 ? kTh_ : vTh_) + hb;
      float* myb = bounce + wn * 4096;
#pragma unroll
      for (int i = 0; i < 2; ++i)
#pragma unroll
        for (int r = 0; r < 4; ++r) {
          const int tloc = wm * 32 + i * 16 + quad * 4 + r;
#pragma unroll
          for (int j = 0; j < 4; ++j) {
            const int d = j * 16 + lrow;
            myb[tloc * 64 + (d ^ tloc)] = fv[i][r][j];
          }
        }
      // per-thread chunk-sum partials over this thread's 8 rows
      float ps[4];
#pragma unroll
      for (int j = 0; j < 4; ++j) {
        ps[j] = 0.f;
#pragma unroll
        for (int i = 0; i < 2; ++i)
#pragma unroll
          for (int r = 0; r < 4; ++r) ps[j] += fv[i][r][j];
        // reduce across quads (lanes lrow, +16, +32, +48)
        ps[j] += __shfl_xor(ps[j], 16);
        ps[j] += __shfl_xor(ps[j], 32);
      }
      __syncthreads();               // S2
      // bounce reads + hi-only transposed global stores
      {
        const int lt = wm * 64 + lane;   // 0..127 over the 2 same-wn waves
        const int e = lt >> 1;           // output row (dim)
        const int tg0 = (lt & 1) * 32;   // 32-t half
#pragma unroll
        for (int s8 = 0; s8 < 4; ++s8) {
          h8 hv;
#pragma unroll
          for (int s = 0; s < 8; ++s) {
            const int t = tg0 + s8 * 8 + s;
            hv[s] = (_Float16)myb[t * 64 + (e ^ t)];
          }
          *(h8*)&th[(size_t)e * T_LEN + bm + tg0 + s8 * 8] = hv;
        }
      }
      // scratch (cs region, dead after S2): wave partials per wn/wm
      if (quad == 0) {
#pragma unroll
        for (int j = 0; j < 4; ++j)
          cs[(wn * 2 + wm) * 64 + j * 16 + lrow] = ps[j];
      }
      __syncthreads();               // S3
      if (wm == 0 && quad == 0) {
        float* dst = (btype == 1 ? ksc_ : vsc_);
        const int c = bm >> 6;
#pragma unroll
        for (int j = 0; j < 4; ++j) {
          const int d = j * 16 + lrow;
          float s = cs[(wn * 2) * 64 + d] + cs[(wn * 2 + 1) * 64 + d];
          dst[((size_t)head * NC + c) * 64 + d] = s;
        }
      }
    }
  }
}

// ---------------------------------------------------------------------------
// Per-(head,chunk) KV^T product via MFMA (hi*hi, num-path). Pure product:
// ksum/vsum now come from the QKV epilogue. Global-direct frags, no LDS.
// ---------------------------------------------------------------------------
__global__ __launch_bounds__(256) void chunk_kvT(
    const _Float16* __restrict__ kTh, const _Float16* __restrict__ vTh,
    float* __restrict__ kvchunk) {
  const int blk = blockIdx.x;  // h*NC + c
  const int h = blk / NC, c = blk % NC;
  const int tid = threadIdx.x;
  const int wave = tid >> 6, lane = tid & 63;
  const int quad = lane >> 4, lrow = lane & 15;
  const size_t hbT = (size_t)h * D_DIM * T_LEN;
  const int tb = c * L_CHK;
  h8 avh[2];
  {
    const _Float16* pa =
        vTh + hbT + (size_t)(wave * 16 + lrow) * T_LEN + tb + quad * 8;
    avh[0] = *(const h8*)pa;
    avh[1] = *(const h8*)(pa + 32);
  }
  f32x4 accv[4];
#pragma unroll
  for (int dt = 0; dt < 4; ++dt) accv[dt] = (f32x4){0.f, 0.f, 0.f, 0.f};
#pragma unroll
  for (int dt = 0; dt < 4; ++dt) {
    const _Float16* pb =
        kTh + hbT + (size_t)(dt * 16 + lrow) * T_LEN + tb + quad * 8;
#pragma unroll
    for (int ks = 0; ks < 2; ++ks) {
      h8 bh = *(const h8*)(pb + ks * 32);
      accv[dt] = __builtin_amdgcn_mfma_f32_16x16x32_f16(avh[ks], bh, accv[dt],
                                                        0, 0, 0);
    }
  }
  float* ob = kvchunk + (size_t)blk * (D_DIM * D_DIM);
#pragma unroll
  for (int dt = 0; dt < 4; ++dt)
#pragma unroll
    for (int r = 0; r < 4; ++r)
      ob[(wave * 16 + quad * 4 + r) * D_DIM + dt * 16 + lrow] = accv[dt][r];
}

// ---------------------------------------------------------------------------
// Fused exclusive prefix scans over chunks. kv state accumulates fp32 but is
// EMITTED as fp16 (num-path tolerance). Vectors stay fp32 (den-path).
// ---------------------------------------------------------------------------
__global__ __launch_bounds__(256) void scan_fused(
    const float* __restrict__ kvchunk, _Float16* __restrict__ kvph,
    const float* __restrict__ kschunk, const float* __restrict__ vschunk,
    float* __restrict__ kspref, float* __restrict__ vspref) {
  int b = blockIdx.x;
  int tid = threadIdx.x;
  if (b < 256) {
    int gid = b * 256 + tid;  // h*4096 + de
    int h = gid >> 12;
    int de = gid & 4095;
    float vals[NC];
#pragma unroll
    for (int c = 0; c < NC; ++c)
      vals[c] = kvchunk[((size_t)(h * NC + c) << 12) + de];
    float run = 0.f;
#pragma unroll
    for (int c = 0; c < NC; ++c) {
      kvph[((size_t)(h * NC + c) << 12) + de] = (_Float16)run;
      run += vals[c];
    }
  } else {
    int gid = (b - 256) * 256 + tid;  // h*64 + d (total 1024)
    int h = gid >> 6, d = gid & 63;
    float kv_[NC], vv_[NC];
#pragma unroll
    for (int c = 0; c < NC; ++c) {
      size_t idx = (size_t)(h * NC + c) * 64 + d;
      kv_[c] = kschunk[idx];
      vv_[c] = vschunk[idx];
    }
    float rk = 0.f, rv = 0.f;
#pragma unroll
    for (int c = 0; c < NC; ++c) {
      size_t idx = (size_t)(h * NC + c) * 64 + d;
      kspref[idx] = rk;
      vspref[idx] = rv;
      rk += kv_[c];
      rv += vv_[c];
    }
  }
}

// ---------------------------------------------------------------------------
// MFMA attention output. One block per (h,c), 4 waves; wave w owns rows
// [w*16, w*16+16) x all 64 e-cols.
//   S = Q K^T split3 (den-critical) -> mask/+1 -> fp16 hi/lo wave-private
//   swizzled LDS; rowsum via ones-MFMA on Sh+Sl (den); S.V = (Sh+Sl).Vh;
//   q.KVpref = qh.KVh (num, fp16 direct); q.kspref split3 (den).
// ---------------------------------------------------------------------------
__global__ __launch_bounds__(256) void attn_mfma(
    const _Float16* __restrict__ qh, const _Float16* __restrict__ ql,
    const _Float16* __restrict__ kh, const _Float16* __restrict__ kl,
    const _Float16* __restrict__ vTh, const _Float16* __restrict__ kvph,
    const float* __restrict__ kspref, const float* __restrict__ vspref,
    _Float16* __restrict__ yh) {
  __shared__ __align__(16) _Float16 sS[2][4][16 * 64];  // [plane][wave][r*64+j]
  const int blk = blockIdx.x;  // h*NC + c
  const int h = blk / NC, c = blk % NC;
  const int tid = threadIdx.x;
  const int wave = tid >> 6, lane = tid & 63;
  const int quad = lane >> 4, lrow = lane & 15;
  const size_t hb = (size_t)h * T_LEN * D_DIM;   // (t,d) arrays
  const size_t hbT = (size_t)h * D_DIM * T_LEN;  // (e,t) arrays
  const int t0 = c * L_CHK;
  const f32x4 z4 = {0.f, 0.f, 0.f, 0.f};
  h8 aqh[2], aql[2];
  {
    const _Float16* pq =
        qh + hb + (size_t)(t0 + wave * 16 + lrow) * D_DIM + quad * 8;
    const _Float16* pql =
        ql + hb + (size_t)(t0 + wave * 16 + lrow) * D_DIM + quad * 8;
    aqh[0] = *(const h8*)pq;
    aqh[1] = *(const h8*)(pq + 32);
    aql[0] = *(const h8*)pql;
    aql[1] = *(const h8*)(pql + 32);
  }
  // S = Q K^T (within-chunk), 4 col-tiles, split3 (den-critical)
  f32x4 sacc[4];
#pragma unroll
  for (int jt = 0; jt < 4; ++jt) sacc[jt] = z4;
#pragma unroll
  for (int jt = 0; jt < 4; ++jt) {
    const _Float16* pk =
        kh + hb + (size_t)(t0 + jt * 16 + lrow) * D_DIM + quad * 8;
    const _Float16* pkl =
        kl + hb + (size_t)(t0 + jt * 16 + lrow) * D_DIM + quad * 8;
#pragma unroll
    for (int ks = 0; ks < 2; ++ks) {
      h8 bh = *(const h8*)(pk + ks * 32);
      h8 bl = *(const h8*)(pkl + ks * 32);
      sacc[jt] = __builtin_amdgcn_mfma_f32_16x16x32_f16(aqh[ks], bh, sacc[jt],
                                                        0, 0, 0);
      sacc[jt] = __builtin_amdgcn_mfma_f32_16x16x32_f16(aqh[ks], bl, sacc[jt],
                                                        0, 0, 0);
      sacc[jt] = __builtin_amdgcn_mfma_f32_16x16x32_f16(aql[ks], bh, sacc[jt],
                                                        0, 0, 0);
    }
  }
  // mask, +1, fp16 split, stage (swizzled: 8-half blocks XOR'd by row&7)
  _Float16* shp = &sS[0][wave][0];
  _Float16* slp = &sS[1][wave][0];
#pragma unroll
  for (int jt = 0; jt < 4; ++jt)
#pragma unroll
    for (int r = 0; r < 4; ++r) {
      const int row = quad * 4 + r;          // band-local row
      const int j = jt * 16 + lrow;          // chunk-local col
      const int rglob = wave * 16 + row;
      float s = (j <= rglob) ? (sacc[jt][r] + 1.f) : 0.f;
      _Float16 hh = (_Float16)s;
      const int adr = row * 64 + ((((j >> 3) ^ (row & 7)) << 3) | (j & 7));
      shp[adr] = hh;
      slp[adr] = (_Float16)(s - (float)hh);
    }
  h8 ash[2], asl[2];
#pragma unroll
  for (int ks = 0; ks < 2; ++ks) {
    const int adr = lrow * 64 + (((ks * 4 + quad) ^ (lrow & 7)) << 3);
    ash[ks] = *(const h8*)&shp[adr];
    asl[ks] = *(const h8*)&slp[adr];
  }
  h8 ones;
#pragma unroll
  for (int m = 0; m < 8; ++m) ones[m] = (_Float16)1.0f;
  f32x4 rs = z4;
#pragma unroll
  for (int ks = 0; ks < 2; ++ks) {
    rs = __builtin_amdgcn_mfma_f32_16x16x32_f16(ash[ks], ones, rs, 0, 0, 0);
    rs = __builtin_amdgcn_mfma_f32_16x16x32_f16(asl[ks], ones, rs, 0, 0, 0);
  }
  f32x4 oacc[4];
#pragma unroll
  for (int et = 0; et < 4; ++et) oacc[et] = z4;
#pragma unroll
  for (int et = 0; et < 4; ++et) {
    const _Float16* pv =
        vTh + hbT + (size_t)(et * 16 + lrow) * T_LEN + t0 + quad * 8;
#pragma unroll
    for (int ks = 0; ks < 2; ++ks) {
      h8 bh = *(const h8*)(pv + ks * 32);
      oacc[et] = __builtin_amdgcn_mfma_f32_16x16x32_f16(ash[ks], bh, oacc[et],
                                                        0, 0, 0);
      oacc[et] = __builtin_amdgcn_mfma_f32_16x16x32_f16(asl[ks], bh, oacc[et],
                                                        0, 0, 0);
    }
  }
  const _Float16* kvp = kvph + ((size_t)blk << 12);
#pragma unroll
  for (int et = 0; et < 4; ++et) {
#pragma unroll
    for (int ks = 0; ks < 2; ++ks) {
      h8 bh = *(const h8*)&kvp[(et * 16 + lrow) * D_DIM + ks * 32 + quad * 8];
      oacc[et] = __builtin_amdgcn_mfma_f32_16x16x32_f16(aqh[ks], bh, oacc[et],
                                                        0, 0, 0);
    }
  }
  const float* ksp = kspref + (size_t)blk * D_DIM;
  f32x4 kacc = z4;
#pragma unroll
  for (int ks = 0; ks < 2; ++ks) {
    const float* pb = ksp + ks * 32 + quad * 8;
    float4 b0 = *(const float4*)pb;
    float4 b1 = *(const float4*)(pb + 4);
    h8 bh, bl;
    split8(b0, b1, bh, bl);
    kacc = __builtin_amdgcn_mfma_f32_16x16x32_f16(aqh[ks], bh, kacc, 0, 0, 0);
    kacc = __builtin_amdgcn_mfma_f32_16x16x32_f16(aqh[ks], bl, kacc, 0, 0, 0);
    kacc = __builtin_amdgcn_mfma_f32_16x16x32_f16(aql[ks], bh, kacc, 0, 0, 0);
  }
  const float* vsp = vspref + (size_t)blk * D_DIM;
#pragma unroll
  for (int r = 0; r < 4; ++r) {
    const int row = wave * 16 + quad * 4 + r;  // chunk-local t
    const float den = (float)(c * L_CHK) + rs[r] + kacc[r];
    const float inv = 1.f / den;
    const size_t ybase = (size_t)(t0 + row) * (H_NUM * D_DIM) + h * D_DIM;
#pragma unroll
    for (int et = 0; et < 4; ++et) {
      const int e = et * 16 + lrow;
      const float num = oacc[et][r] + vsp[e];
      yh[ybase + e] = (_Float16)(num * inv);
    }
  }
}

// ---------------------------------------------------------------------------
extern "C" void kernel_launch(void* const* d_in, const int* in_sizes, int n_in,
                              void* d_out, int out_size, void* d_ws,
                              size_t ws_size, hipStream_t stream) {
  const float* x = (const float*)d_in[0];       // (1,2048,1024)
  const float* w_attn = (const float*)d_in[1];  // (3072,1024)
  const float* w_proj = (const float*)d_in[2];  // (1024,1024)
  const float* cosb = (const float*)d_in[3];    // (2048,64)
  const float* sinb = (const float*)d_in[4];    // (2048,64)
  float* out = (float*)d_out;                   // (2048,1024)

  char* ws = (char*)d_ws;
  const size_t MB = 1048576;
  // 0..8MB: kvchunk fp32; 8..12MB: kvph fp16 prefix
  float* kvchunk = (float*)ws;
  _Float16* kvph = (_Float16*)(ws + 8 * MB);
  // 12..16MB hole: chunk sum vectors (written by QKV epilogue) + prefixes
  float* kschunk = (float*)(ws + 12 * MB + 4096);
  float* vschunk = (float*)(ws + 12 * MB + 4096 + 131072);
  float* kspref = (float*)(ws + 12 * MB + 4096 + 262144);
  float* vspref = (float*)(ws + 12 * MB + 4096 + 393216);
  // 16..44MB: fp16 q,k hi/lo (t,d); kT hi, vT hi (d/e, t)
  _Float16* qh = (_Float16*)(ws + 16 * MB);
  _Float16* ql = (_Float16*)(ws + 20 * MB);
  _Float16* kh = (_Float16*)(ws + 24 * MB);
  _Float16* kl = (_Float16*)(ws + 28 * MB);
  _Float16* kTh = (_Float16*)(ws + 32 * MB);
  _Float16* vTh = (_Float16*)(ws + 40 * MB);
  // 48..56MB: xh/xl (live split->QKV GEMM); then yh.
  _Float16* xh = (_Float16*)(ws + 48 * MB);
  _Float16* xl = (_Float16*)(ws + 52 * MB);
  _Float16* yh = (_Float16*)(ws + 48 * MB);
  // 56..68MB: wah/wal (live split->QKV GEMM).
  _Float16* wah = (_Float16*)(ws + 56 * MB);
  _Float16* wal = (_Float16*)(ws + 62 * MB);
  // 68..70MB: wph (live whole call).
  _Float16* wph = (_Float16*)(ws + 68 * MB);

  // 0) fused splits (scale 64, undone in epilogues); w_proj hi-only
  split3_f16<<<3072, 256, 0, stream>>>(x, xh, xl, w_attn, wah, wal, w_proj,
                                       wph);

  // 1) qkv GEMM (type-uniform blocks; v hi*hi) + RoPE + exact ksum/vsum
  {
    dim3 grid(QKV_N / 128, T_LEN / 64);   // 24 x 32 = 768 blocks
    gemm_nt_f16<128, true, true><<<grid, 256, 0, stream>>>(
        xh, xl, wah, wal, nullptr, cosb, sinb, qh, ql, kh, kl, kTh, vTh,
        kschunk, vschunk, T_LEN, QKV_N, C_DIM, 1.f / 4096.f);
  }
  // 2) per-chunk KV^T product (hi*hi)
  chunk_kvT<<<H_NUM * NC, 256, 0, stream>>>(kTh, vTh, kvchunk);
  // 3) fused prefix scans (kv -> fp16; vectors fp32)
  scan_fused<<<260, 256, 0, stream>>>(kvchunk, kvph, kschunk, vschunk,
                                      kspref, vspref);
  // 4) MFMA attention output -> yh (T, H*D) fp16
  attn_mfma<<<H_NUM * NC, 256, 0, stream>>>(qh, ql, kh, kl, vTh, kvph,
                                            kspref, vspref, yh);
  // 5) out = y @ w_proj^T (plain fp16, 64x64 tiles, 512 blocks): 2^-6
  {
    dim3 grid(C_DIM / 64, T_LEN / 64);    // 16 x 32 = 512 blocks
    gemm_nt_f16<64, false, false><<<grid, 256, 0, stream>>>(
        yh, nullptr, wph, nullptr, out, nullptr, nullptr, nullptr, nullptr,
        nullptr, nullptr, nullptr, nullptr, nullptr, nullptr, T_LEN, C_DIM,
        C_DIM, 1.f / 64.f);
  }
}